// Round 8
// baseline (410.484 us; speedup 1.0000x reference)
//
#include <hip/hip_runtime.h>
#include <hip/hip_bf16.h>

#define B_   32
#define N_   4096
#define D_   768
#define HID_ 256

#define SX 64.0f
#define SW 1024.0f
#define INV_S (1.0f / 65536.0f)

typedef unsigned long long ull;
typedef _Float16 half8 __attribute__((ext_vector_type(8)));
typedef float f32x16 __attribute__((ext_vector_type(16)));

__device__ __forceinline__ void gload_lds16(const void* g, void* l) {
  __builtin_amdgcn_global_load_lds(
      (const __attribute__((address_space(1))) void*)g,
      (__attribute__((address_space(3))) void*)l, 16, 0, 0);
}

// ---------------- Kernel P: fused prep: W-split (blocks 0..95) + label proj (96..127)
// Whi/Wlo layout: [96 chunks][256 hid][8 k] f16 — the 32x32x16 A-fragment order.
__global__ __launch_bounds__(256) void prep_kernel(
    const float* __restrict__ W1, _Float16* __restrict__ whi,
    _Float16* __restrict__ wlo, const float* __restrict__ lc,
    const float* __restrict__ Wp, const float* __restrict__ bp,
    float* __restrict__ lbl_n) {
  if (blockIdx.x < 96) {
    int c = blockIdx.x;
    int h = threadIdx.x;
    half8 vh, vl;
#pragma unroll
    for (int j = 0; j < 8; ++j) {
      float w = W1[(size_t)(c * 8 + j) * 256 + h] * SW;
      _Float16 hi = (_Float16)w;
      vh[j] = hi;
      vl[j] = (_Float16)(w - (float)hi);
    }
    *(half8*)&whi[((size_t)c * 256 + h) * 8] = vh;
    *(half8*)&wlo[((size_t)c * 256 + h) * 8] = vl;
    return;
  }
  int b = blockIdx.x - 96;
  int t = threadIdx.x;
  __shared__ float s_lc[128];
  __shared__ float s_out[768];
  __shared__ float s_red[4];

  if (t < 128) s_lc[t] = lc[b * 128 + t];
  __syncthreads();

  float sumsq = 0.f;
  for (int d = t; d < D_; d += 256) {
    float acc = bp[d];
    for (int k = 0; k < 128; ++k) acc += s_lc[k] * Wp[k * D_ + d];
    s_out[d] = acc;
    sumsq += acc * acc;
  }
  for (int off = 32; off >= 1; off >>= 1) sumsq += __shfl_xor(sumsq, off);
  if ((t & 63) == 0) s_red[t >> 6] = sumsq;
  __syncthreads();
  float tot = s_red[0] + s_red[1] + s_red[2] + s_red[3];
  float inv = 1.f / fmaxf(sqrtf(tot), 1e-12f);
  for (int d = t; d < D_; d += 256) lbl_n[b * D_ + d] = s_out[d] * inv;
}

// ---------------- Kernel B: split-f16 MFMA score kernel, v10 ----------------
// v8 geometry (4 waves, 128 patches x 256 hid, acc 8 x f32x16) but W staged via
// global_load_lds (width 16) into a linear LDS mirror of the frag-ordered pack:
// zero VGPR round-trip, zero in-block duplication on the vector path.
// Counted vmcnt(2) per stage (gloads drained, depth-2 X regs stay in flight);
// sched_barrier(0) fences pin vmem order; one s_barrier per K16 stage.
__global__ __launch_bounds__(256, 2) void score10_kernel(
    const float* __restrict__ X, const _Float16* __restrict__ Whi,
    const _Float16* __restrict__ Wlo, const float* __restrict__ b1,
    const float* __restrict__ W2, const float* __restrict__ b2,
    const float* __restrict__ lbl_n, float* __restrict__ scores) {
  __shared__ __align__(16) _Float16 sWh[2][2][256][8];    // [buf][k8][hid][8] 16KB
  __shared__ __align__(16) _Float16 sWl[2][2][256][8];    // 16KB
  __shared__ __align__(16) _Float16 sB[2][2][2][128][8];  // [buf][hl][k8][row][8] 16KB
  __shared__ __align__(16) float sLbl[768];
  __shared__ float sB1[256], sW2[256];
  __shared__ float sVs[2][128];
  __shared__ float sLsc[128];

  const int t  = threadIdx.x;
  const int w  = t >> 6;     // wave id (uniform per wave)
  const int l  = t & 63;
  const int l5 = l >> 5;
  const int ln = l & 31;
  const int hh = w >> 1;
  const int pg = w & 1;
  const int pb = blockIdx.x * 128;
  const int batch = pb >> 12;

  // staging role: thread t owns patch row r, k8-half h2
  const int r  = t >> 1;
  const int h2 = t & 1;
  const float* xrow = X + (size_t)(pb + r) * D_ + h2 * 8;

  const char* gWh = (const char*)Whi;   // stage slab = 8KB, frag-ordered
  const char* gWl = (const char*)Wlo;

  f32x16 acc[4][2];
#pragma unroll
  for (int mt = 0; mt < 4; ++mt)
#pragma unroll
    for (int bt = 0; bt < 2; ++bt)
#pragma unroll
      for (int q = 0; q < 16; ++q) acc[mt][bt][q] = 0.f;

  float sq = 0.f, dt = 0.f;

#define GLOAD_W(S, BUF)                                                        \
  {                                                                            \
    const char* srcH = gWh + (size_t)(S) * 8192;                               \
    const char* srcL = gWl + (size_t)(S) * 8192;                               \
    char* dH = (char*)&sWh[BUF][0][0][0] + w * 1024;                           \
    char* dL = (char*)&sWl[BUF][0][0][0] + w * 1024;                           \
    gload_lds16(srcH + t * 16, dH);                                            \
    gload_lds16(srcH + 4096 + t * 16, dH + 4096);                              \
    gload_lds16(srcL + t * 16, dL);                                            \
    gload_lds16(srcL + 4096 + t * 16, dL + 4096);                              \
  }

#define SPLIT_STORE(BUF, V0, V1, SIDX)                                         \
  {                                                                            \
    half8 nbh, nbl;                                                            \
    _Pragma("unroll")                                                          \
    for (int j = 0; j < 8; ++j) {                                              \
      float xv = (j < 4) ? (&(V0).x)[j] : (&(V1).x)[j - 4];                    \
      float lv = sLbl[(SIDX) * 16 + h2 * 8 + j];                               \
      sq += xv * xv;                                                           \
      dt += xv * lv;                                                           \
      float xs = xv * SX;                                                      \
      _Float16 hi = (_Float16)xs;                                              \
      nbh[j] = hi;                                                             \
      nbl[j] = (_Float16)(xs - (float)hi);                                     \
    }                                                                          \
    *(half8*)&sB[BUF][0][h2][r][0] = nbh;                                      \
    *(half8*)&sB[BUF][1][h2][r][0] = nbl;                                      \
  }

#define MFMA_STAGE(C)                                                          \
  {                                                                            \
    half8 ah[4], al[4], bh[2], bl[2];                                          \
    _Pragma("unroll")                                                          \
    for (int mt = 0; mt < 4; ++mt) {                                           \
      ah[mt] = *(const half8*)&sWh[C][l5][hh * 128 + mt * 32 + ln][0];         \
      al[mt] = *(const half8*)&sWl[C][l5][hh * 128 + mt * 32 + ln][0];         \
    }                                                                          \
    _Pragma("unroll")                                                          \
    for (int bt = 0; bt < 2; ++bt) {                                           \
      bh[bt] = *(const half8*)&sB[C][0][l5][pg * 64 + bt * 32 + ln][0];        \
      bl[bt] = *(const half8*)&sB[C][1][l5][pg * 64 + bt * 32 + ln][0];        \
    }                                                                          \
    __builtin_amdgcn_s_setprio(1);                                             \
    _Pragma("unroll")                                                          \
    for (int mt = 0; mt < 4; ++mt)                                             \
      _Pragma("unroll")                                                        \
      for (int bt = 0; bt < 2; ++bt)                                           \
        acc[mt][bt] = __builtin_amdgcn_mfma_f32_32x32x16_f16(                  \
            ah[mt], bh[bt], acc[mt][bt], 0, 0, 0);                             \
    _Pragma("unroll")                                                          \
    for (int mt = 0; mt < 4; ++mt)                                             \
      _Pragma("unroll")                                                        \
      for (int bt = 0; bt < 2; ++bt)                                           \
        acc[mt][bt] = __builtin_amdgcn_mfma_f32_32x32x16_f16(                  \
            ah[mt], bl[bt], acc[mt][bt], 0, 0, 0);                             \
    _Pragma("unroll")                                                          \
    for (int mt = 0; mt < 4; ++mt)                                             \
      _Pragma("unroll")                                                        \
      for (int bt = 0; bt < 2; ++bt)                                           \
        acc[mt][bt] = __builtin_amdgcn_mfma_f32_32x32x16_f16(                  \
            al[mt], bh[bt], acc[mt][bt], 0, 0, 0);                             \
    __builtin_amdgcn_s_setprio(0);                                             \
  }

#define STAGE_END()                                                            \
  {                                                                            \
    asm volatile("s_waitcnt vmcnt(2) lgkmcnt(0)" ::: "memory");                \
    __builtin_amdgcn_sched_barrier(0);                                         \
    __builtin_amdgcn_s_barrier();                                              \
  }

  // ---- prologue ----
  GLOAD_W(0, 0)                         // W(0) -> buf0 (async, drained by syncthreads)
  for (int i = t; i < D_; i += 256) sLbl[i] = lbl_n[batch * D_ + i];
  sB1[t] = b1[t];
  sW2[t] = W2[t];
  float4 x00 = *(const float4*)(xrow + 0);
  float4 x01 = *(const float4*)(xrow + 4);
  __syncthreads();                      // vmcnt(0)+lgkm(0)+barrier: W(0), sLbl ready

  SPLIT_STORE(0, x00, x01, 0)
  float4 xa0 = *(const float4*)(xrow + 16);   // X(1)
  float4 xa1 = *(const float4*)(xrow + 20);
  float4 xb0 = *(const float4*)(xrow + 32);   // X(2)
  float4 xb1 = *(const float4*)(xrow + 36);
  asm volatile("s_waitcnt lgkmcnt(0)" ::: "memory");
  __builtin_amdgcn_s_barrier();         // sB[0] visible

  // ---- main loop: 48 K16 stages ----
  for (int ss = 0; ss < 24; ++ss) {
    // ===== even stage S = 2ss: buf0; consumes xa (X(S+1)) =====
    {
      const int S = 2 * ss;
      GLOAD_W(S + 1, 1)                 // W(S+1) -> buf1
      __builtin_amdgcn_sched_barrier(0);
      const int s3 = (S + 3 > 47) ? 47 : S + 3;
      float4 nx0 = *(const float4*)(xrow + s3 * 16);
      float4 nx1 = *(const float4*)(xrow + s3 * 16 + 4);
      __builtin_amdgcn_sched_barrier(0);
      MFMA_STAGE(0)
      SPLIT_STORE(1, xa0, xa1, S + 1)
      xa0 = nx0; xa1 = nx1;
      STAGE_END()
    }
    // ===== odd stage S = 2ss+1: buf1; consumes xb (X(S+1)) =====
    {
      const int S = 2 * ss + 1;
      if (S < 47) {
        GLOAD_W(S + 1, 0)               // W(S+1) -> buf0
        __builtin_amdgcn_sched_barrier(0);
        const int s3 = (S + 3 > 47) ? 47 : S + 3;
        float4 nx0 = *(const float4*)(xrow + s3 * 16);
        float4 nx1 = *(const float4*)(xrow + s3 * 16 + 4);
        __builtin_amdgcn_sched_barrier(0);
        MFMA_STAGE(1)
        SPLIT_STORE(0, xb0, xb1, S + 1)
        xb0 = nx0; xb1 = nx1;
        STAGE_END()
      } else {
        MFMA_STAGE(1)                   // last stage: reads only
      }
    }
  }
#undef GLOAD_W
#undef SPLIT_STORE
#undef MFMA_STAGE
#undef STAGE_END

  // ---- epilogue ----
  sq += __shfl_xor(sq, 1);
  dt += __shfl_xor(dt, 1);
  if (h2 == 0) sLsc[r] = dt / fmaxf(sqrtf(sq), 1e-12f);

  float vsb[2] = {0.f, 0.f};
#pragma unroll
  for (int mt = 0; mt < 4; ++mt) {
#pragma unroll
    for (int rq = 0; rq < 4; ++rq) {
      const int hb = hh * 128 + mt * 32 + rq * 8 + l5 * 4;
      const float4 b1v = *(const float4*)&sB1[hb];
      const float4 w2v = *(const float4*)&sW2[hb];
#pragma unroll
      for (int j = 0; j < 4; ++j) {
        float h0 = acc[mt][0][rq * 4 + j] * INV_S + (&b1v.x)[j];
        float h1 = acc[mt][1][rq * 4 + j] * INV_S + (&b1v.x)[j];
        vsb[0] += fmaxf(h0, 0.f) * (&w2v.x)[j];
        vsb[1] += fmaxf(h1, 0.f) * (&w2v.x)[j];
      }
    }
  }
  vsb[0] += __shfl_xor(vsb[0], 32);
  vsb[1] += __shfl_xor(vsb[1], 32);
  if (l < 32) {
    sVs[hh][pg * 64 + l]      = vsb[0];
    sVs[hh][pg * 64 + 32 + l] = vsb[1];
  }
  __syncthreads();

  if (t < 128) {
    float vst = sVs[0][t] + sVs[1][t] + b2[0];
    scores[pb + t] = 0.4f * vst + 0.6f * sLsc[t];
  }
}

// ---------------- Kernel C: fused per-batch exact top-K + gather ----------------
// Tournament with cached per-wave maxima (exact: descending, tie->lower idx),
// then in-kernel gather of the selected rows + float-encoded indices.
__global__ __launch_bounds__(256) void topk_gather_kernel(
    const float* __restrict__ scores, const float* __restrict__ feats,
    float* __restrict__ out_feats, float* __restrict__ out_idx_f, int K) {
  int b = blockIdx.x;
  int t = threadIdx.x;
  int wv = t >> 6, l = t & 63;
  __shared__ ull swm[4];
  __shared__ int sIdx[256];

  ull keys[16];
#pragma unroll
  for (int j = 0; j < 16; ++j) {
    int i = (j << 8) + t;  // coalesced
    float s = scores[(b << 12) + i];
    unsigned u = __float_as_uint(s);
    u = (u & 0x80000000u) ? ~u : (u | 0x80000000u);
    keys[j] = ((ull)u << 32) | (unsigned)(4095 - i);  // tie -> lower index wins
  }
  ull cur = 0;
#pragma unroll
  for (int j = 0; j < 16; ++j) cur = keys[j] > cur ? keys[j] : cur;

  {  // initial per-wave reduce
    ull wb = cur;
#pragma unroll
    for (int off = 1; off < 64; off <<= 1) {
      ull o = __shfl_xor(wb, off);
      wb = o > wb ? o : wb;
    }
    if (l == 0) swm[wv] = wb;
  }
  __syncthreads();

  for (int sel = 0; sel < K; ++sel) {
    ull m0 = swm[0] > swm[1] ? swm[0] : swm[1];
    ull m1 = swm[2] > swm[3] ? swm[2] : swm[3];
    ull best = m0 > m1 ? m0 : m1;
    if (t == 0) {
      int id = 4095 - (int)(unsigned)(best & 0xFFFFFFFFull);
      sIdx[sel] = id;
      out_idx_f[b * K + sel] = (float)id;
    }
    if (swm[wv] == best) {  // only the owning wave re-reduces
      if (cur == best) {
        cur = 0;
#pragma unroll
        for (int j = 0; j < 16; ++j)
          cur = (keys[j] < best && keys[j] > cur) ? keys[j] : cur;
      }
      ull wb = cur;
#pragma unroll
      for (int off = 1; off < 64; off <<= 1) {
        ull o = __shfl_xor(wb, off);
        wb = o > wb ? o : wb;
      }
      if (l == 0) swm[wv] = wb;
    }
    __syncthreads();
  }

  // gather: K rows x 192 float4 each, coalesced within rows
  const float4* src = (const float4*)feats;
  float4* dst = (float4*)out_feats;
  const int total = K * 192;
  for (int u = t; u < total; u += 256) {
    int rr = u / 192;
    int q  = u - rr * 192;
    int id = sIdx[rr];
    dst[((size_t)b * K + rr) * 192 + q] = src[((size_t)b * N_ + id) * 192 + q];
  }
}

extern "C" void kernel_launch(void* const* d_in, const int* in_sizes, int n_in,
                              void* d_out, int out_size, void* d_ws, size_t ws_size,
                              hipStream_t stream) {
  const float* feats = (const float*)d_in[0];
  const float* lc    = (const float*)d_in[1];
  const float* W1    = (const float*)d_in[2];
  const float* b1    = (const float*)d_in[3];
  const float* W2    = (const float*)d_in[4];
  const float* b2    = (const float*)d_in[5];
  const float* Wp    = (const float*)d_in[6];
  const float* bp    = (const float*)d_in[7];
  int K = out_size / (B_ * (D_ + 1));  // 192

  float* ws_f    = (float*)d_ws;
  float* lbl_n   = ws_f;                              // 32*768
  float* scoresv = ws_f + B_ * D_;                    // 32*4096
  size_t off = (size_t)B_ * D_ + (size_t)B_ * N_ + B_ * 256;
  off = (off + 3) & ~(size_t)3;
  _Float16* whi = (_Float16*)(ws_f + off);            // 96*256*8 halves
  _Float16* wlo = whi + (size_t)96 * 256 * 8;

  float* out_f     = (float*)d_out;
  float* out_idx_f = out_f + (size_t)B_ * K * D_;

  prep_kernel<<<128, 256, 0, stream>>>(W1, whi, wlo, lc, Wp, bp, lbl_n);
  score10_kernel<<<(B_ * N_) / 128, 256, 0, stream>>>(feats, whi, wlo, b1, W2, b2,
                                                      lbl_n, scoresv);
  topk_gather_kernel<<<B_, 256, 0, stream>>>(scoresv, feats, out_f, out_idx_f, K);
}

// Round 9
// 371.861 us; speedup vs baseline: 1.1039x; 1.1039x over previous
//
#include <hip/hip_runtime.h>
#include <hip/hip_bf16.h>

#define B_   32
#define N_   4096
#define D_   768
#define HID_ 256

#define SX 64.0f
#define SW 1024.0f
#define INV_S (1.0f / 65536.0f)

typedef unsigned long long ull;
typedef _Float16 half8 __attribute__((ext_vector_type(8)));
typedef _Float16 half4 __attribute__((ext_vector_type(4)));
typedef float f32x16 __attribute__((ext_vector_type(16)));

__device__ __forceinline__ void gload_lds16(const void* g, void* l) {
  __builtin_amdgcn_global_load_lds(
      (const __attribute__((address_space(1))) void*)g,
      (__attribute__((address_space(3))) void*)l, 16, 0, 0);
}

// ---------------- Kernel P: fused prep: W-split (blocks 0..95) + label proj (96..127)
// Whi/Wlo layout: [96 chunks][256 hid][8 k] f16 — the 32x32x16 A-fragment order.
__global__ __launch_bounds__(256) void prep_kernel(
    const float* __restrict__ W1, _Float16* __restrict__ whi,
    _Float16* __restrict__ wlo, const float* __restrict__ lc,
    const float* __restrict__ Wp, const float* __restrict__ bp,
    float* __restrict__ lbl_n) {
  if (blockIdx.x < 96) {
    int c = blockIdx.x;
    int h = threadIdx.x;
    half8 vh, vl;
#pragma unroll
    for (int j = 0; j < 8; ++j) {
      float w = W1[(size_t)(c * 8 + j) * 256 + h] * SW;
      _Float16 hi = (_Float16)w;
      vh[j] = hi;
      vl[j] = (_Float16)(w - (float)hi);
    }
    *(half8*)&whi[((size_t)c * 256 + h) * 8] = vh;
    *(half8*)&wlo[((size_t)c * 256 + h) * 8] = vl;
    return;
  }
  int b = blockIdx.x - 96;
  int t = threadIdx.x;
  __shared__ float s_lc[128];
  __shared__ float s_out[768];
  __shared__ float s_red[4];

  if (t < 128) s_lc[t] = lc[b * 128 + t];
  __syncthreads();

  float sumsq = 0.f;
  for (int d = t; d < D_; d += 256) {
    float acc = bp[d];
    for (int k = 0; k < 128; ++k) acc += s_lc[k] * Wp[k * D_ + d];
    s_out[d] = acc;
    sumsq += acc * acc;
  }
  for (int off = 32; off >= 1; off >>= 1) sumsq += __shfl_xor(sumsq, off);
  if ((t & 63) == 0) s_red[t >> 6] = sumsq;
  __syncthreads();
  float tot = s_red[0] + s_red[1] + s_red[2] + s_red[3];
  float inv = 1.f / fmaxf(sqrtf(tot), 1e-12f);
  for (int d = t; d < D_; d += 256) lbl_n[b * D_ + d] = s_out[d] * inv;
}

// ---------------- Kernel B: split-f16 MFMA score kernel, v12 ----------------
// Block: 4 waves (256 thr) = 64 patches x 256 hid. Wave w: hid quarter w*64
// (mt=2 A-tiles), ALL 64 patches (bt=2 B-tiles); acc = 4 x f32x16 = 64 VGPR.
// Small wave-tile -> 3 waves/SIMD (launch_bounds(256,3)), LDS 46KB -> 3 blocks/CU:
// 3 independent barrier domains de-phase LDS-read vs MFMA phases across blocks.
// W via global_load_lds dbuf (16KB/stage); X one float4/thread/stage, depth-2.
// Per stage: 8 ds_read_b128 + 12 MFMA + split(4 floats) + vmcnt(1)/lgkm(0)/barrier.
__global__ __launch_bounds__(256, 3) void score12_kernel(
    const float* __restrict__ X, const _Float16* __restrict__ Whi,
    const _Float16* __restrict__ Wlo, const float* __restrict__ b1,
    const float* __restrict__ W2, const float* __restrict__ b2,
    const float* __restrict__ lbl_n, float* __restrict__ scores) {
  __shared__ __align__(16) _Float16 sWh[2][2][256][8];  // [buf][k8][hid][8] 16KB
  __shared__ __align__(16) _Float16 sWl[2][2][256][8];  // 16KB
  __shared__ __align__(16) _Float16 sB[2][2][2][64][8]; // [buf][hl][k8][row][8] 8KB
  __shared__ __align__(16) float sLbl[768];
  __shared__ float sB1[256], sW2[256];
  __shared__ float sVs[4][64];
  __shared__ float sLsc[64];

  const int t  = threadIdx.x;
  const int w  = t >> 6;
  const int l  = t & 63;
  const int l5 = l >> 5;
  const int ln = l & 31;
  const int pb = blockIdx.x * 64;
  const int batch = pb >> 12;

  // staging role: thread t owns patch row r, k-quarter kq (4 floats/stage)
  const int r  = t >> 2;
  const int kq = t & 3;
  const float* xbase = X + (size_t)(pb + r) * D_ + kq * 4;

  f32x16 acc[2][2];
#pragma unroll
  for (int mt = 0; mt < 2; ++mt)
#pragma unroll
    for (int bt = 0; bt < 2; ++bt)
#pragma unroll
      for (int q = 0; q < 16; ++q) acc[mt][bt][q] = 0.f;

  float sq = 0.f, dt = 0.f;

#define GLOAD_W(S, BUF)                                                        \
  {                                                                            \
    const char* srcH = (const char*)Whi + (size_t)(S) * 8192;                  \
    const char* srcL = (const char*)Wlo + (size_t)(S) * 8192;                  \
    char* dH = (char*)&sWh[BUF][0][0][0] + w * 1024;                           \
    char* dL = (char*)&sWl[BUF][0][0][0] + w * 1024;                           \
    gload_lds16(srcH + t * 16, dH);                                            \
    gload_lds16(srcH + 4096 + t * 16, dH + 4096);                              \
    gload_lds16(srcL + t * 16, dL);                                            \
    gload_lds16(srcL + 4096 + t * 16, dL + 4096);                              \
  }

#define SPLIT_STORE(BUF, XV, SIDX)                                             \
  {                                                                            \
    half4 nh, nl;                                                              \
    const float4 lv = *(const float4*)&sLbl[(SIDX) * 16 + kq * 4];             \
    _Pragma("unroll")                                                          \
    for (int j = 0; j < 4; ++j) {                                              \
      float xv = (&(XV).x)[j];                                                 \
      sq += xv * xv;                                                           \
      dt += xv * (&lv.x)[j];                                                   \
      float xs = xv * SX;                                                      \
      _Float16 hi = (_Float16)xs;                                              \
      nh[j] = hi;                                                              \
      nl[j] = (_Float16)(xs - (float)hi);                                      \
    }                                                                          \
    *(half4*)&sB[BUF][0][kq >> 1][r][(kq & 1) * 4] = nh;                       \
    *(half4*)&sB[BUF][1][kq >> 1][r][(kq & 1) * 4] = nl;                       \
  }

  // ---- prologue ----
  GLOAD_W(0, 0)
  float4 x0 = *(const float4*)(xbase);        // X window 0
  float4 xc = *(const float4*)(xbase + 16);   // X window 1
  for (int i = t; i < D_; i += 256) sLbl[i] = lbl_n[batch * D_ + i];
  sB1[t] = b1[t];
  sW2[t] = W2[t];
  __syncthreads();                            // drains gload W(0) + sLbl

  SPLIT_STORE(0, x0, 0)
  asm volatile("s_waitcnt lgkmcnt(0)" ::: "memory");
  __builtin_amdgcn_s_barrier();               // sB buf0 visible

  // ---- main loop: stages 0..46 (stage 47 peeled: MFMA only) ----
  for (int S = 0; S < 47; ++S) {
    const int c = S & 1;
    GLOAD_W(S + 1, c ^ 1)
    const int s2 = (S + 2 > 47) ? 47 : S + 2;
    float4 xn = *(const float4*)(xbase + s2 * 16);
    __builtin_amdgcn_sched_barrier(0);

    half8 ah[2], al[2], bh[2], bl[2];
#pragma unroll
    for (int mt = 0; mt < 2; ++mt) {
      ah[mt] = *(const half8*)&sWh[c][l5][w * 64 + mt * 32 + ln][0];
      al[mt] = *(const half8*)&sWl[c][l5][w * 64 + mt * 32 + ln][0];
    }
#pragma unroll
    for (int bt = 0; bt < 2; ++bt) {
      bh[bt] = *(const half8*)&sB[c][0][l5][bt * 32 + ln][0];
      bl[bt] = *(const half8*)&sB[c][1][l5][bt * 32 + ln][0];
    }
    __builtin_amdgcn_s_setprio(1);
#pragma unroll
    for (int mt = 0; mt < 2; ++mt)
#pragma unroll
      for (int bt = 0; bt < 2; ++bt)
        acc[mt][bt] = __builtin_amdgcn_mfma_f32_32x32x16_f16(
            ah[mt], bh[bt], acc[mt][bt], 0, 0, 0);
#pragma unroll
    for (int mt = 0; mt < 2; ++mt)
#pragma unroll
      for (int bt = 0; bt < 2; ++bt)
        acc[mt][bt] = __builtin_amdgcn_mfma_f32_32x32x16_f16(
            ah[mt], bl[bt], acc[mt][bt], 0, 0, 0);
#pragma unroll
    for (int mt = 0; mt < 2; ++mt)
#pragma unroll
      for (int bt = 0; bt < 2; ++bt)
        acc[mt][bt] = __builtin_amdgcn_mfma_f32_32x32x16_f16(
            al[mt], bh[bt], acc[mt][bt], 0, 0, 0);
    __builtin_amdgcn_s_setprio(0);

    SPLIT_STORE(c ^ 1, xc, S + 1)
    xc = xn;
    // drain this stage's 4 gloads (X prefetch stays in flight), publish ds_writes
    asm volatile("s_waitcnt vmcnt(1) lgkmcnt(0)" ::: "memory");
    __builtin_amdgcn_sched_barrier(0);
    __builtin_amdgcn_s_barrier();
  }

  // ---- stage 47: MFMA only (buf 1) ----
  {
    half8 ah[2], al[2], bh[2], bl[2];
#pragma unroll
    for (int mt = 0; mt < 2; ++mt) {
      ah[mt] = *(const half8*)&sWh[1][l5][w * 64 + mt * 32 + ln][0];
      al[mt] = *(const half8*)&sWl[1][l5][w * 64 + mt * 32 + ln][0];
    }
#pragma unroll
    for (int bt = 0; bt < 2; ++bt) {
      bh[bt] = *(const half8*)&sB[1][0][l5][bt * 32 + ln][0];
      bl[bt] = *(const half8*)&sB[1][1][l5][bt * 32 + ln][0];
    }
#pragma unroll
    for (int mt = 0; mt < 2; ++mt)
#pragma unroll
      for (int bt = 0; bt < 2; ++bt) {
        acc[mt][bt] = __builtin_amdgcn_mfma_f32_32x32x16_f16(
            ah[mt], bh[bt], acc[mt][bt], 0, 0, 0);
      }
#pragma unroll
    for (int mt = 0; mt < 2; ++mt)
#pragma unroll
      for (int bt = 0; bt < 2; ++bt) {
        acc[mt][bt] = __builtin_amdgcn_mfma_f32_32x32x16_f16(
            ah[mt], bl[bt], acc[mt][bt], 0, 0, 0);
        acc[mt][bt] = __builtin_amdgcn_mfma_f32_32x32x16_f16(
            al[mt], bh[bt], acc[mt][bt], 0, 0, 0);
      }
  }
  __syncthreads();
#undef GLOAD_W
#undef SPLIT_STORE

  // ---- epilogue ----
  sq += __shfl_xor(sq, 1);  dt += __shfl_xor(dt, 1);
  sq += __shfl_xor(sq, 2);  dt += __shfl_xor(dt, 2);
  if ((t & 3) == 0) sLsc[r] = dt / fmaxf(sqrtf(sq), 1e-12f);

  float vsb[2] = {0.f, 0.f};
#pragma unroll
  for (int mt = 0; mt < 2; ++mt) {
#pragma unroll
    for (int rq = 0; rq < 4; ++rq) {
      const int hb = w * 64 + mt * 32 + rq * 8 + l5 * 4;
      const float4 b1v = *(const float4*)&sB1[hb];
      const float4 w2v = *(const float4*)&sW2[hb];
#pragma unroll
      for (int j = 0; j < 4; ++j) {
        float h0 = acc[mt][0][rq * 4 + j] * INV_S + (&b1v.x)[j];
        float h1 = acc[mt][1][rq * 4 + j] * INV_S + (&b1v.x)[j];
        vsb[0] += fmaxf(h0, 0.f) * (&w2v.x)[j];
        vsb[1] += fmaxf(h1, 0.f) * (&w2v.x)[j];
      }
    }
  }
  vsb[0] += __shfl_xor(vsb[0], 32);
  vsb[1] += __shfl_xor(vsb[1], 32);
  if (l < 32) {
    sVs[w][l]      = vsb[0];
    sVs[w][32 + l] = vsb[1];
  }
  __syncthreads();

  if (t < 64) {
    float vst = sVs[0][t] + sVs[1][t] + sVs[2][t] + sVs[3][t] + b2[0];
    scores[pb + t] = 0.4f * vst + 0.6f * sLsc[t];
  }
}

// ---------------- Kernel C: per-batch exact top-K, cached wave-max tournament --
__global__ __launch_bounds__(256) void topk3_kernel(
    const float* __restrict__ scores, int* __restrict__ out_idx,
    float* __restrict__ out_idx_f, int K) {
  int b = blockIdx.x;
  int t = threadIdx.x;
  int wv = t >> 6, l = t & 63;
  __shared__ ull swm[4];

  ull keys[16];
#pragma unroll
  for (int j = 0; j < 16; ++j) {
    int i = (j << 8) + t;  // coalesced
    float s = scores[(b << 12) + i];
    unsigned u = __float_as_uint(s);
    u = (u & 0x80000000u) ? ~u : (u | 0x80000000u);
    keys[j] = ((ull)u << 32) | (unsigned)(4095 - i);  // tie -> lower index wins
  }
  ull cur = 0;
#pragma unroll
  for (int j = 0; j < 16; ++j) cur = keys[j] > cur ? keys[j] : cur;

  {  // initial per-wave reduce
    ull wb = cur;
#pragma unroll
    for (int off = 1; off < 64; off <<= 1) {
      ull o = __shfl_xor(wb, off);
      wb = o > wb ? o : wb;
    }
    if (l == 0) swm[wv] = wb;
  }
  __syncthreads();

  for (int sel = 0; sel < K; ++sel) {
    ull m0 = swm[0] > swm[1] ? swm[0] : swm[1];
    ull m1 = swm[2] > swm[3] ? swm[2] : swm[3];
    ull best = m0 > m1 ? m0 : m1;
    if (t == 0) {
      int id = 4095 - (int)(unsigned)(best & 0xFFFFFFFFull);
      out_idx[b * K + sel] = id;
      out_idx_f[b * K + sel] = (float)id;
    }
    if (swm[wv] == best) {  // only the owning wave re-reduces
      if (cur == best) {
        cur = 0;
#pragma unroll
        for (int j = 0; j < 16; ++j)
          cur = (keys[j] < best && keys[j] > cur) ? keys[j] : cur;
      }
      ull wb = cur;
#pragma unroll
      for (int off = 1; off < 64; off <<= 1) {
        ull o = __shfl_xor(wb, off);
        wb = o > wb ? o : wb;
      }
      if (l == 0) swm[wv] = wb;
    }
    __syncthreads();
  }
}

// ---------------- Kernel D: gather ----------------
__global__ __launch_bounds__(192) void gather_kernel(
    const float* __restrict__ feats, const int* __restrict__ idx,
    float* __restrict__ out_feats, int K) {
  int i = blockIdx.x;
  int b = blockIdx.y;
  int id = idx[b * K + i];
  const float4* src = (const float4*)&feats[((size_t)b * N_ + id) * D_];
  float4* dst = (float4*)&out_feats[((size_t)b * K + i) * D_];
  dst[threadIdx.x] = src[threadIdx.x];
}

extern "C" void kernel_launch(void* const* d_in, const int* in_sizes, int n_in,
                              void* d_out, int out_size, void* d_ws, size_t ws_size,
                              hipStream_t stream) {
  const float* feats = (const float*)d_in[0];
  const float* lc    = (const float*)d_in[1];
  const float* W1    = (const float*)d_in[2];
  const float* b1    = (const float*)d_in[3];
  const float* W2    = (const float*)d_in[4];
  const float* b2    = (const float*)d_in[5];
  const float* Wp    = (const float*)d_in[6];
  const float* bp    = (const float*)d_in[7];
  int K = out_size / (B_ * (D_ + 1));  // 192

  float* ws_f    = (float*)d_ws;
  float* lbl_n   = ws_f;                              // 32*768
  float* scoresv = ws_f + B_ * D_;                    // 32*4096
  int*   topidx  = (int*)(ws_f + B_ * D_ + B_ * N_);  // 32*192
  size_t off = (size_t)B_ * D_ + (size_t)B_ * N_ + B_ * 256;
  off = (off + 3) & ~(size_t)3;
  _Float16* whi = (_Float16*)(ws_f + off);            // 96*256*8 halves
  _Float16* wlo = whi + (size_t)96 * 256 * 8;

  float* out_f     = (float*)d_out;
  float* out_idx_f = out_f + (size_t)B_ * K * D_;

  prep_kernel<<<128, 256, 0, stream>>>(W1, whi, wlo, lc, Wp, bp, lbl_n);
  score12_kernel<<<(B_ * N_) / 64, 256, 0, stream>>>(feats, whi, wlo, b1, W2, b2,
                                                     lbl_n, scoresv);
  topk3_kernel<<<B_, 256, 0, stream>>>(scoresv, topidx, out_idx_f, K);
  gather_kernel<<<dim3(K, B_), 192, 0, stream>>>(feats, topidx, out_f, K);
}